// Round 2
// baseline (1358.831 us; speedup 1.0000x reference)
//
#include <hip/hip_runtime.h>
#include <hip/hip_bf16.h>
#include <math.h>

// Problem constants
#define N_T   16
#define BSZ   128
#define DDIM  4096
#define KROWS (N_T * BSZ)          // 2048
#define CHW   (3 * 64 * 64)        // 12288
#define S_PIC (BSZ * CHW)          // 1572864
#define T_MSE (N_T * S_PIC)        // 25165824
#define KPOS  (KROWS * (N_T - 1))  // 30720

#define NBLK        1024           // persistent grid: 4 blocks/CU x 256 CUs
#define MSE_JOBS    3072           // 16 slabs x 192 jobs (64 KB each)
#define MSE_BLOCKS  3072

typedef short  bf16x8 __attribute__((ext_vector_type(8)));   // 8 bf16 = 4 VGPRs
typedef float  f32x4  __attribute__((ext_vector_type(4)));

// ---------------- reductions ----------------
__device__ __forceinline__ float waveReduceSum(float v) {
    for (int off = 32; off > 0; off >>= 1) v += __shfl_down(v, off, 64);
    return v;
}
// 256-thread blocks only. Leading sync makes repeated calls safe (WAR on s[]).
__device__ __forceinline__ float blockReduceSum(float v) {
    __shared__ float s[8];
    __syncthreads();
    int lane = threadIdx.x & 63, wid = threadIdx.x >> 6;
    v = waveReduceSum(v);
    if (lane == 0) s[wid] = v;
    __syncthreads();
    v = (threadIdx.x < 4) ? s[threadIdx.x] : 0.0f;
    if (wid == 0) v = waveReduceSum(v);
    return v;   // valid in thread 0
}

// ---------------- device-scope grid barrier (all NBLK blocks co-resident) ---
// Release: every thread fences (vmcnt drain + L2 writeback, cross-XCD safe),
// then thread 0 arrives at a device-scope counter. Last block resets the
// counter and bumps the generation with release semantics. Acquire: fence
// after the spin invalidates L1/L2 so other blocks' plain stores are visible.
__device__ __forceinline__ void grid_sync(int* cnt, int* gen) {
    __syncthreads();
    __threadfence();
    __syncthreads();
    if (threadIdx.x == 0) {
        const int g = __hip_atomic_load(gen, __ATOMIC_RELAXED, __HIP_MEMORY_SCOPE_AGENT);
        if (__hip_atomic_fetch_add(cnt, 1, __ATOMIC_ACQ_REL, __HIP_MEMORY_SCOPE_AGENT)
            == NBLK - 1) {
            __hip_atomic_store(cnt, 0, __ATOMIC_RELAXED, __HIP_MEMORY_SCOPE_AGENT);
            __hip_atomic_fetch_add(gen, 1, __ATOMIC_RELEASE, __HIP_MEMORY_SCOPE_AGENT);
        } else {
            while (__hip_atomic_load(gen, __ATOMIC_ACQUIRE, __HIP_MEMORY_SCOPE_AGENT) == g)
                __builtin_amdgcn_s_sleep(8);
        }
    }
    __syncthreads();
    __threadfence();
}

// ---------------- MSE job body (m13 copy pattern) ----------------
// Job t: slab n = t & 15, chunk bx = t >> 4; 8192 contiguous floats.
// Accumulates per-thread partials into s0..s3 (no reduction here).
__device__ __forceinline__ void mse_job(const float* __restrict__ pic,
                                        const float* __restrict__ dec,
                                        int t, float& s0, float& s1,
                                        float& s2, float& s3) {
    const int n = t & (N_T - 1), bx = t >> 4;
    const size_t off = (size_t)n * S_PIC + (size_t)bx * 8192 + threadIdx.x * 4;
    const ptrdiff_t doff = (ptrdiff_t)(((n + 1) & (N_T - 1)) - n) * S_PIC;
    const float* p = pic + off;
    const float* d = dec + off + doff;
#pragma unroll
    for (int k = 0; k < 8; k++) {
        float4 a = *(const float4*)(p + k * 1024);
        float4 b = *(const float4*)(d + k * 1024);
        float dx = a.x - b.x, dy = a.y - b.y, dz = a.z - b.z, dw = a.w - b.w;
        s0 += dx * dx; s1 += dy * dy; s2 += dz * dz; s3 += dw * dw;
    }
}

// ============================================================================
// FUSED persistent kernel: phase A (norm + MSE) | B (pure GEMM) | C (LSE).
// 1024 blocks x 256 thr, 4 blocks/CU guaranteed (VGPR<=128 via launch_bounds,
// LDS 16.5 KB). Phase separation removes MSE<->GEMM memory interference and
// all inter-dispatch boundaries.
// ============================================================================
__global__ __launch_bounds__(256, 4) void fused_kernel(
        const float* __restrict__ pic, const float* __restrict__ dec,
        const float* __restrict__ h, __hip_bfloat16* __restrict__ hbuf,
        float* __restrict__ Cpart, float* __restrict__ acc,
        int* __restrict__ bar, float* __restrict__ out) {
    __shared__ ushort As[128 * 32];   // 8 KB (phase B); phase C reuses As as srow
    __shared__ ushort Bs[128 * 32];   // 8 KB
    __shared__ float scale_s;
    const int tid = threadIdx.x;
    int* const cnt = bar;
    int* const gen = bar + 1;

    // ---------------- Phase A: norm (2 rows/block) + MSE (3 jobs/block) -----
    {
        const ushort* hu = (const ushort*)h;   // silence unused warnings path
        (void)hu;
#pragma unroll
        for (int rr = 0; rr < 2; rr++) {
            const int row = (blockIdx.x << 1) | rr;
            const float* rp = h + (size_t)row * DDIM + tid * 16;
            // single pass: 16 floats/thread cached in registers
            float4 v0 = *(const float4*)(rp);
            float4 v1 = *(const float4*)(rp + 4);
            float4 v2 = *(const float4*)(rp + 8);
            float4 v3 = *(const float4*)(rp + 12);
            float ss = v0.x * v0.x + v0.y * v0.y + v0.z * v0.z + v0.w * v0.w
                     + v1.x * v1.x + v1.y * v1.y + v1.z * v1.z + v1.w * v1.w
                     + v2.x * v2.x + v2.y * v2.y + v2.z * v2.z + v2.w * v2.w
                     + v3.x * v3.x + v3.y * v3.y + v3.z * v3.z + v3.w * v3.w;
            ss = blockReduceSum(ss);
            if (tid == 0) scale_s = 1.0f / fmaxf(sqrtf(ss), 1e-8f);
            __syncthreads();
            const float sc = scale_s;
            __hip_bfloat16 t[16];
            t[0]  = __float2bfloat16(v0.x * sc); t[1]  = __float2bfloat16(v0.y * sc);
            t[2]  = __float2bfloat16(v0.z * sc); t[3]  = __float2bfloat16(v0.w * sc);
            t[4]  = __float2bfloat16(v1.x * sc); t[5]  = __float2bfloat16(v1.y * sc);
            t[6]  = __float2bfloat16(v1.z * sc); t[7]  = __float2bfloat16(v1.w * sc);
            t[8]  = __float2bfloat16(v2.x * sc); t[9]  = __float2bfloat16(v2.y * sc);
            t[10] = __float2bfloat16(v2.z * sc); t[11] = __float2bfloat16(v2.w * sc);
            t[12] = __float2bfloat16(v3.x * sc); t[13] = __float2bfloat16(v3.y * sc);
            t[14] = __float2bfloat16(v3.z * sc); t[15] = __float2bfloat16(v3.w * sc);
            __hip_bfloat16* ob = hbuf + (size_t)row * DDIM + tid * 16;
            *(bf16x8*)(ob)     = *(const bf16x8*)(t);
            *(bf16x8*)(ob + 8) = *(const bf16x8*)(t + 8);
        }
        // MSE: 3 jobs per block, one block-reduce, one atomic.
        float s0 = 0.f, s1 = 0.f, s2 = 0.f, s3 = 0.f;
#pragma unroll
        for (int q = 0; q < 3; q++)
            mse_job(pic, dec, blockIdx.x * 3 + q, s0, s1, s2, s3);
        float msum = blockReduceSum((s0 + s1) + (s2 + s3));
        if (tid == 0) atomicAdd(acc, msum);   // acc pre-zeroed by host memset
    }

    grid_sync(cnt, gen);   // hbuf fully written, MSE traffic done

    // ---------------- Phase B: pure GEMM, split-K=4, 1024 jobs --------------
    {
        int bid = blockIdx.x;
        // XCD-aware bijective swizzle (1024 % 8 == 0)
        bid = (bid & 7) * (NBLK >> 3) + (bid >> 3);
        const int kz = bid >> 8;                 // split-K slice 0..3
        const int bi = (bid >> 4) & 15, bj = bid & 15;
        const int wave = tid >> 6, lane = tid & 63;
        const int wm = wave >> 1, wn = wave & 1;        // 2x2 wave grid
        const int quad = lane >> 4, l16 = lane & 15;
        const ushort* X = (const ushort*)hbuf;

        f32x4 acc_r[4][4];
#pragma unroll
        for (int i = 0; i < 4; i++)
#pragma unroll
            for (int j = 0; j < 4; j++) acc_r[i][j] = (f32x4){0.f, 0.f, 0.f, 0.f};

        const int srw = lane >> 2;           // 0..15
        const int scl = (lane & 3) * 8;      // 0,8,16,24
        const ushort* Ag0 = X + (size_t)(bi * 128 + wave * 16       + srw) * DDIM + scl;
        const ushort* Ag1 = X + (size_t)(bi * 128 + (wave + 4) * 16 + srw) * DDIM + scl;
        const ushort* Bg0 = X + (size_t)(bj * 128 + wave * 16       + srw) * DDIM + scl;
        const ushort* Bg1 = X + (size_t)(bj * 128 + (wave + 4) * 16 + srw) * DDIM + scl;
        ushort* Al0 = As + wave * 512;
        ushort* Al1 = As + (wave + 4) * 512;
        ushort* Bl0 = Bs + wave * 512;
        ushort* Bl1 = Bs + (wave + 4) * 512;

        const int k0 = kz * (DDIM / 4), k1 = k0 + (DDIM / 4);
        for (int kk = k0; kk < k1; kk += 32) {
            __syncthreads();
            __builtin_amdgcn_global_load_lds(
                (const __attribute__((address_space(1))) unsigned int*)(Ag0 + kk),
                (__attribute__((address_space(3))) unsigned int*)Al0, 16, 0, 0);
            __builtin_amdgcn_global_load_lds(
                (const __attribute__((address_space(1))) unsigned int*)(Ag1 + kk),
                (__attribute__((address_space(3))) unsigned int*)Al1, 16, 0, 0);
            __builtin_amdgcn_global_load_lds(
                (const __attribute__((address_space(1))) unsigned int*)(Bg0 + kk),
                (__attribute__((address_space(3))) unsigned int*)Bl0, 16, 0, 0);
            __builtin_amdgcn_global_load_lds(
                (const __attribute__((address_space(1))) unsigned int*)(Bg1 + kk),
                (__attribute__((address_space(3))) unsigned int*)Bl1, 16, 0, 0);
            __syncthreads();

            bf16x8 a[4], b[4];
#pragma unroll
            for (int t = 0; t < 4; t++)
                a[t] = *(const bf16x8*)(As + (wm * 64 + t * 16 + l16) * 32 + quad * 8);
#pragma unroll
            for (int t = 0; t < 4; t++)
                b[t] = *(const bf16x8*)(Bs + (wn * 64 + t * 16 + l16) * 32 + quad * 8);
#pragma unroll
            for (int mt = 0; mt < 4; mt++)
#pragma unroll
                for (int nt = 0; nt < 4; nt++)
                    acc_r[mt][nt] = __builtin_amdgcn_mfma_f32_16x16x32_bf16(
                        a[mt], b[nt], acc_r[mt][nt], 0, 0, 0);
        }

        float* Cp = Cpart + (size_t)kz * KROWS * KROWS;
#pragma unroll
        for (int mt = 0; mt < 4; mt++) {
#pragma unroll
            for (int r = 0; r < 4; r++) {
                const int row = bi * 128 + wm * 64 + mt * 16 + quad * 4 + r;
                float* o = Cp + (size_t)row * KROWS + bj * 128 + wn * 64 + l16;
#pragma unroll
                for (int nt = 0; nt < 4; nt++) o[nt * 16] = 2.0f * acc_r[mt][nt][r];
            }
        }
    }

    grid_sync(cnt, gen);   // Cpart fully written

    // ---------------- Phase C: fixed-shift LSE (2 rows/block) ---------------
    {
        float* srow = (float*)As;          // 8 KB, reuse phase-B LDS
        float lsum = 0.0f;
#pragma unroll
        for (int rr = 0; rr < 2; rr++) {
            const int i = (blockIdx.x << 1) | rr;
            __syncthreads();               // protect srow vs prev-iter tail read
            const float* r0 = Cpart + (size_t)i * KROWS;
            for (int j = tid * 4; j < KROWS; j += 1024) {
                float4 s = *(const float4*)(r0 + j);
#pragma unroll
                for (int p = 1; p < 4; p++) {
                    const float4 b = *(const float4*)(r0 + (size_t)p * KROWS * KROWS + j);
                    s.x += b.x; s.y += b.y; s.z += b.z; s.w += b.w;
                }
                *(float4*)(srow + j) = s;
            }
            __syncthreads();
            const int ires = i & (BSZ - 1);
            float se = 0.0f;
            for (int j = tid; j < KROWS; j += 256)
                if ((j & (BSZ - 1)) != ires) se += __expf(srow[j] - 2.0f);
            se = blockReduceSum(se);
            if (tid == 0) {
                const float neg_lse = 2.0f + __logf(se);
#pragma unroll
                for (int t = 0; t < N_T; t++) {
                    const int j = ires + t * BSZ;
                    if (j == i) continue;
                    const float x = neg_lse - srow[j];
                    lsum += (x > 0.0f) ? (x + log1pf(expf(-x))) : log1pf(expf(x));
                }
            }
        }
        if (tid == 0) atomicAdd(acc + 1, lsum);
    }

    grid_sync(cnt, gen);   // all loss atomics done

    if (blockIdx.x == 0 && threadIdx.x == 0) {
        const float mse = atomicAdd(acc + 0, 0.0f);   // coherent read-back
        const float lh  = atomicAdd(acc + 1, 0.0f);
        out[0] = mse / (float)T_MSE + lh / (float)KPOS;
    }
}

// ============================================================================
// Fallback kernels (small-workspace paths) — unchanged round-1 structure.
// ============================================================================
__device__ __forceinline__ void mse_block(const float* __restrict__ pic,
                                          const float* __restrict__ dec,
                                          float* __restrict__ acc,
                                          int n, int bx) {
    float s0 = 0.f, s1 = 0.f, s2 = 0.f, s3 = 0.f;
    mse_job(pic, dec, (bx << 4) | n, s0, s1, s2, s3);
    float sum = blockReduceSum((s0 + s1) + (s2 + s3));
    if (threadIdx.x == 0) atomicAdd(acc, sum);
}

__global__ void norm_kernel(const float* __restrict__ h,
                            __hip_bfloat16* __restrict__ hb,
                            float* __restrict__ acc, int zero_acc) {
    if (zero_acc && blockIdx.x == 0 && threadIdx.x < 64)
        acc[threadIdx.x] = 0.0f;
    const int row = blockIdx.x;
    const float* r = h + (size_t)row * DDIM;
    float ss = 0.0f;
    for (int k = threadIdx.x * 8; k < DDIM; k += blockDim.x * 8) {
        float4 v0 = *(const float4*)(r + k);
        float4 v1 = *(const float4*)(r + k + 4);
        ss += v0.x * v0.x + v0.y * v0.y + v0.z * v0.z + v0.w * v0.w;
        ss += v1.x * v1.x + v1.y * v1.y + v1.z * v1.z + v1.w * v1.w;
    }
    ss = blockReduceSum(ss);
    __shared__ float scale_s;
    if (threadIdx.x == 0) scale_s = 1.0f / fmaxf(sqrtf(ss), 1e-8f);
    __syncthreads();
    const float sc = scale_s;
    __hip_bfloat16* ob = hb + (size_t)row * DDIM;
    for (int k = threadIdx.x * 8; k < DDIM; k += blockDim.x * 8) {
        float4 v0 = *(const float4*)(r + k);
        float4 v1 = *(const float4*)(r + k + 4);
        __hip_bfloat16 t[8];
        t[0] = __float2bfloat16(v0.x * sc); t[1] = __float2bfloat16(v0.y * sc);
        t[2] = __float2bfloat16(v0.z * sc); t[3] = __float2bfloat16(v0.w * sc);
        t[4] = __float2bfloat16(v1.x * sc); t[5] = __float2bfloat16(v1.y * sc);
        t[6] = __float2bfloat16(v1.z * sc); t[7] = __float2bfloat16(v1.w * sc);
        *(bf16x8*)(ob + k) = *(const bf16x8*)t;
    }
}

template<int NKZ>
__global__ __launch_bounds__(256) void mega_kernel(const ushort* __restrict__ X,
                                                   float* __restrict__ Cpart,
                                                   const float* __restrict__ pic,
                                                   const float* __restrict__ dec,
                                                   float* __restrict__ acc) {
    __shared__ ushort As[128 * 32];
    __shared__ ushort Bs[128 * 32];
    constexpr int NG = NKZ * 256;
    int bid = blockIdx.x;
    if (bid >= NG) {
        const int t = bid - NG;
        mse_block(pic, dec, acc, t & (N_T - 1), t >> 4);
        return;
    }
    bid = (bid & 7) * (NG >> 3) + (bid >> 3);
    const int kz = bid >> 8;
    const int bi = (bid >> 4) & 15, bj = bid & 15;
    const int tid = threadIdx.x;
    const int wave = tid >> 6, lane = tid & 63;
    const int wm = wave >> 1, wn = wave & 1;
    const int quad = lane >> 4, l16 = lane & 15;
    f32x4 acc_r[4][4];
#pragma unroll
    for (int i = 0; i < 4; i++)
#pragma unroll
        for (int j = 0; j < 4; j++) acc_r[i][j] = (f32x4){0.f, 0.f, 0.f, 0.f};
    const int srw = lane >> 2;
    const int scl = (lane & 3) * 8;
    const ushort* Ag0 = X + (size_t)(bi * 128 + wave * 16       + srw) * DDIM + scl;
    const ushort* Ag1 = X + (size_t)(bi * 128 + (wave + 4) * 16 + srw) * DDIM + scl;
    const ushort* Bg0 = X + (size_t)(bj * 128 + wave * 16       + srw) * DDIM + scl;
    const ushort* Bg1 = X + (size_t)(bj * 128 + (wave + 4) * 16 + srw) * DDIM + scl;
    ushort* Al0 = As + wave * 512;
    ushort* Al1 = As + (wave + 4) * 512;
    ushort* Bl0 = Bs + wave * 512;
    ushort* Bl1 = Bs + (wave + 4) * 512;
    constexpr int KS = DDIM / NKZ;
    const int k0 = kz * KS, k1 = k0 + KS;
    for (int kk = k0; kk < k1; kk += 32) {
        __syncthreads();
        __builtin_amdgcn_global_load_lds(
            (const __attribute__((address_space(1))) unsigned int*)(Ag0 + kk),
            (__attribute__((address_space(3))) unsigned int*)Al0, 16, 0, 0);
        __builtin_amdgcn_global_load_lds(
            (const __attribute__((address_space(1))) unsigned int*)(Ag1 + kk),
            (__attribute__((address_space(3))) unsigned int*)Al1, 16, 0, 0);
        __builtin_amdgcn_global_load_lds(
            (const __attribute__((address_space(1))) unsigned int*)(Bg0 + kk),
            (__attribute__((address_space(3))) unsigned int*)Bl0, 16, 0, 0);
        __builtin_amdgcn_global_load_lds(
            (const __attribute__((address_space(1))) unsigned int*)(Bg1 + kk),
            (__attribute__((address_space(3))) unsigned int*)Bl1, 16, 0, 0);
        __syncthreads();
        bf16x8 a[4], b[4];
#pragma unroll
        for (int t = 0; t < 4; t++)
            a[t] = *(const bf16x8*)(As + (wm * 64 + t * 16 + l16) * 32 + quad * 8);
#pragma unroll
        for (int t = 0; t < 4; t++)
            b[t] = *(const bf16x8*)(Bs + (wn * 64 + t * 16 + l16) * 32 + quad * 8);
#pragma unroll
        for (int mt = 0; mt < 4; mt++)
#pragma unroll
            for (int nt = 0; nt < 4; nt++)
                acc_r[mt][nt] = __builtin_amdgcn_mfma_f32_16x16x32_bf16(
                    a[mt], b[nt], acc_r[mt][nt], 0, 0, 0);
    }
    float* Cp = Cpart + (size_t)kz * KROWS * KROWS;
#pragma unroll
    for (int mt = 0; mt < 4; mt++) {
#pragma unroll
        for (int r = 0; r < 4; r++) {
            const int row = bi * 128 + wm * 64 + mt * 16 + quad * 4 + r;
            float* o = Cp + (size_t)row * KROWS + bj * 128 + wn * 64 + l16;
#pragma unroll
            for (int nt = 0; nt < 4; nt++) o[nt * 16] = 2.0f * acc_r[mt][nt][r];
        }
    }
}

__global__ __launch_bounds__(256) void mse_kernel(const float* __restrict__ pic,
                                                  const float* __restrict__ dec,
                                                  float* __restrict__ acc) {
    mse_block(pic, dec, acc, blockIdx.y, blockIdx.x);
}

template<int NKZ>
__global__ void lse_kernel(const float* __restrict__ Cpart,
                           float* __restrict__ acc,
                           float* __restrict__ out) {
    const int i = blockIdx.x;
    __shared__ float srow[KROWS];
    const float* r0 = Cpart + (size_t)i * KROWS;
    for (int j = threadIdx.x * 4; j < KROWS; j += blockDim.x * 4) {
        float4 s = *(const float4*)(r0 + j);
#pragma unroll
        for (int p = 1; p < NKZ; p++) {
            float4 b = *(const float4*)(r0 + (size_t)p * KROWS * KROWS + j);
            s.x += b.x; s.y += b.y; s.z += b.z; s.w += b.w;
        }
        *(float4*)(srow + j) = s;
    }
    __syncthreads();
    const int ires = i & (BSZ - 1);
    float se = 0.0f;
    for (int j = threadIdx.x; j < KROWS; j += blockDim.x)
        if ((j & (BSZ - 1)) != ires) se += __expf(srow[j] - 2.0f);
    se = blockReduceSum(se);
    if (threadIdx.x == 0) {
        const float neg_lse = 2.0f + __logf(se);
        float loss = 0.0f;
#pragma unroll
        for (int t = 0; t < N_T; t++) {
            const int j = ires + t * BSZ;
            if (j == i) continue;
            const float x = neg_lse - srow[j];
            loss += (x > 0.0f) ? (x + log1pf(expf(-x))) : log1pf(expf(x));
        }
        atomicAdd(acc + 1, loss);
        __threadfence();
        const int old = atomicAdd((int*)acc + 8, 1);
        if (old == KROWS - 1) {
            const float mse = atomicAdd(acc + 0, 0.0f);
            const float lh  = atomicAdd(acc + 1, 0.0f);
            out[0] = mse / (float)T_MSE + lh / (float)KPOS;
        }
    }
}

extern "C" void kernel_launch(void* const* d_in, const int* in_sizes, int n_in,
                              void* d_out, int out_size, void* d_ws, size_t ws_size,
                              hipStream_t stream) {
    const float* pic = (const float*)d_in[0];
    float* dec = (float*)d_in[1];
    const float* h = (const float*)d_in[2];
    float* out = (float*)d_out;

    float* acc = (float*)d_ws;  // acc[0]=mse, acc[1]=loss_h, int[8]=counter, int[32..33]=barrier
    int* bar = (int*)d_ws + 32;
    const size_t hbuf_bytes = (size_t)KROWS * DDIM * sizeof(__hip_bfloat16);   // 16 MB
    const size_t part_bytes = (size_t)KROWS * KROWS * sizeof(float);           // 16.78 MB

    if (ws_size >= 256 + hbuf_bytes + 4 * part_bytes) {
        // Fused persistent-grid path: one dispatch for the whole pipeline.
        __hip_bfloat16* hbuf = (__hip_bfloat16*)((char*)d_ws + 256);
        float* Cpart = (float*)((char*)d_ws + 256 + hbuf_bytes);
        hipMemsetAsync(d_ws, 0, 256, stream);   // zero acc + barrier state
        fused_kernel<<<NBLK, 256, 0, stream>>>(pic, dec, h, hbuf, Cpart, acc, bar, out);
    } else if (ws_size >= 256 + hbuf_bytes + 2 * part_bytes) {
        // Split-K=2 overlapped 3-kernel path (round-0 structure).
        __hip_bfloat16* hbuf = (__hip_bfloat16*)((char*)d_ws + 256);
        float* Cpart = (float*)((char*)d_ws + 256 + hbuf_bytes);
        norm_kernel<<<KROWS, 256, 0, stream>>>(h, hbuf, acc, 1);
        mega_kernel<2><<<2 * 256 + MSE_BLOCKS, 256, 0, stream>>>(
            (const ushort*)hbuf, Cpart, pic, dec, acc);
        lse_kernel<2><<<KROWS, 256, 0, stream>>>(Cpart, acc, out);
    } else {
        // Sequential fallback: dec buffer as scratch.
        hipMemsetAsync(d_ws, 0, 256, stream);
        __hip_bfloat16* hbuf = (__hip_bfloat16*)dec;
        float* Cpart = (float*)((char*)dec + hbuf_bytes);
        mse_kernel<<<dim3(MSE_BLOCKS / N_T, N_T), 256, 0, stream>>>(pic, dec, acc);
        norm_kernel<<<KROWS, 256, 0, stream>>>(h, hbuf, acc, 0);
        mega_kernel<2><<<2 * 256, 256, 0, stream>>>(
            (const ushort*)hbuf, Cpart, pic, dec, acc);
        lse_kernel<2><<<KROWS, 256, 0, stream>>>(Cpart, acc, out);
    }
}

// Round 3
// 338.931 us; speedup vs baseline: 4.0092x; 4.0092x over previous
//
#include <hip/hip_runtime.h>
#include <hip/hip_bf16.h>
#include <math.h>

// Problem constants
#define N_T   16
#define BSZ   128
#define DDIM  4096
#define KROWS (N_T * BSZ)          // 2048
#define CHW   (3 * 64 * 64)        // 12288
#define S_PIC (BSZ * CHW)          // 1572864
#define T_MSE (N_T * S_PIC)        // 25165824
#define KPOS  (KROWS * (N_T - 1))  // 30720

#define MSE_BLOCKS  3072           // 16 slabs x 192 blocks (64 KB each)

typedef short  bf16x8 __attribute__((ext_vector_type(8)));   // 8 bf16 = 4 VGPRs
typedef float  f32x4  __attribute__((ext_vector_type(4)));

// ---------------- reductions ----------------
__device__ __forceinline__ float waveReduceSum(float v) {
    for (int off = 32; off > 0; off >>= 1) v += __shfl_down(v, off, 64);
    return v;
}
__device__ __forceinline__ float blockReduceSum(float v) {
    __shared__ float s[8];
    int lane = threadIdx.x & 63, wid = threadIdx.x >> 6;
    v = waveReduceSum(v);
    if (lane == 0) s[wid] = v;
    __syncthreads();
    int nw = (blockDim.x + 63) >> 6;
    v = (threadIdx.x < nw) ? s[threadIdx.x] : 0.0f;
    if (wid == 0) v = waveReduceSum(v);
    return v;   // valid in thread 0
}

// ---------------- MSE block body (m13 copy pattern) ----------------
// Slab n, block bx: 8192 contiguous floats at n*S_PIC + bx*8192.
__device__ __forceinline__ void mse_block(const float* __restrict__ pic,
                                          const float* __restrict__ dec,
                                          float* __restrict__ acc,
                                          int n, int bx) {
    const size_t off = (size_t)n * S_PIC + (size_t)bx * 8192 + threadIdx.x * 4;
    const ptrdiff_t doff = (ptrdiff_t)(((n + 1) & (N_T - 1)) - n) * S_PIC;
    const float* p = pic + off;
    const float* d = dec + off + doff;
    float s0 = 0.f, s1 = 0.f, s2 = 0.f, s3 = 0.f;
#pragma unroll
    for (int k = 0; k < 8; k++) {
        float4 a = *(const float4*)(p + k * 1024);
        float4 b = *(const float4*)(d + k * 1024);
        float dx = a.x - b.x, dy = a.y - b.y, dz = a.z - b.z, dw = a.w - b.w;
        s0 += dx * dx; s1 += dy * dy; s2 += dz * dz; s3 += dw * dw;
    }
    float sum = (s0 + s1) + (s2 + s3);
    sum = blockReduceSum(sum);
    if (threadIdx.x == 0) atomicAdd(acc, sum);
}

// ---------------- K2: single-pass row normalization of h -> bf16 ------------
// 256 thr x 16 floats = 4096; row held in registers across the reduce
// (saves the second 33 MB read from L2). Dedicated kernel -> no register
// pressure interaction with the GEMM (round-2 lesson).
__global__ __launch_bounds__(256) void norm_kernel(const float* __restrict__ h,
                                                   __hip_bfloat16* __restrict__ hb,
                                                   float* __restrict__ acc,
                                                   int zero_acc) {
    if (zero_acc && blockIdx.x == 0 && threadIdx.x < 64)
        acc[threadIdx.x] = 0.0f;   // zero mse/loss accumulators + done-counter

    const int row = blockIdx.x;
    const float* rp = h + (size_t)row * DDIM + threadIdx.x * 16;
    float4 v0 = *(const float4*)(rp);
    float4 v1 = *(const float4*)(rp + 4);
    float4 v2 = *(const float4*)(rp + 8);
    float4 v3 = *(const float4*)(rp + 12);
    float ss = v0.x * v0.x + v0.y * v0.y + v0.z * v0.z + v0.w * v0.w
             + v1.x * v1.x + v1.y * v1.y + v1.z * v1.z + v1.w * v1.w
             + v2.x * v2.x + v2.y * v2.y + v2.z * v2.z + v2.w * v2.w
             + v3.x * v3.x + v3.y * v3.y + v3.z * v3.z + v3.w * v3.w;
    ss = blockReduceSum(ss);
    __shared__ float scale_s;
    if (threadIdx.x == 0) scale_s = 1.0f / fmaxf(sqrtf(ss), 1e-8f);
    __syncthreads();
    const float sc = scale_s;
    __hip_bfloat16 t[16];
    t[0]  = __float2bfloat16(v0.x * sc); t[1]  = __float2bfloat16(v0.y * sc);
    t[2]  = __float2bfloat16(v0.z * sc); t[3]  = __float2bfloat16(v0.w * sc);
    t[4]  = __float2bfloat16(v1.x * sc); t[5]  = __float2bfloat16(v1.y * sc);
    t[6]  = __float2bfloat16(v1.z * sc); t[7]  = __float2bfloat16(v1.w * sc);
    t[8]  = __float2bfloat16(v2.x * sc); t[9]  = __float2bfloat16(v2.y * sc);
    t[10] = __float2bfloat16(v2.z * sc); t[11] = __float2bfloat16(v2.w * sc);
    t[12] = __float2bfloat16(v3.x * sc); t[13] = __float2bfloat16(v3.y * sc);
    t[14] = __float2bfloat16(v3.z * sc); t[15] = __float2bfloat16(v3.w * sc);
    __hip_bfloat16* ob = hb + (size_t)row * DDIM + threadIdx.x * 16;
    *(bf16x8*)(ob)     = *(const bf16x8*)(t);
    *(bf16x8*)(ob + 8) = *(const bf16x8*)(t + 8);
}

// ---------------- Mega kernel: fused GEMM (split-K=NKZ) + MSE ----------------
// GEMM path now uses the T3 "minimum 2-phase" pipeline: double-buffered LDS,
// next tile's global_load_lds issued BEFORE the current tile's ds_read+MFMA,
// raw s_barrier + inline-asm vmcnt(0) only AFTER the MFMAs. This hides the
// global->LDS latency (the m97 2-barrier structure exposes it fully per
// 32-K step, the suspected N=2048 limiter). LDS = 33 KB -> up to 4 blocks/CU.
template<int NKZ>
__global__ __launch_bounds__(256) void mega_kernel(const ushort* __restrict__ X,
                                                   float* __restrict__ Cpart,
                                                   const float* __restrict__ pic,
                                                   const float* __restrict__ dec,
                                                   float* __restrict__ acc) {
    __shared__ ushort As0[128 * 32];   // 8 KB each, row-major 128x32
    __shared__ ushort Bs0[128 * 32];
    __shared__ ushort As1[128 * 32];
    __shared__ ushort Bs1[128 * 32];
    constexpr int NG = NKZ * 256;
    int bid = blockIdx.x;

    if (bid >= NG) {
        const int t = bid - NG;
        mse_block(pic, dec, acc, t & (N_T - 1), t >> 4);
        return;
    }

    // XCD-aware bijective swizzle (NG % 8 == 0).
    bid = (bid & 7) * (NG >> 3) + (bid >> 3);

    const int kz = bid >> 8;                 // split-K slice
    const int bi = (bid >> 4) & 15, bj = bid & 15;
    const int tid  = threadIdx.x;
    const int wave = tid >> 6, lane = tid & 63;
    const int wm = wave >> 1, wn = wave & 1;        // 2x2 wave grid
    const int quad = lane >> 4, l16 = lane & 15;

    f32x4 acc_r[4][4];
#pragma unroll
    for (int i = 0; i < 4; i++)
#pragma unroll
        for (int j = 0; j < 4; j++) acc_r[i][j] = (f32x4){0.f, 0.f, 0.f, 0.f};

    // Staging geometry: 8 chunks of 16 rows per tile; wave w loads chunks
    // {w, w+4}. LDS dest is wave-uniform base + lane*16 B (linear layout).
    const int srw = lane >> 2;           // 0..15
    const int scl = (lane & 3) * 8;      // 0,8,16,24
    const ushort* Ag0 = X + (size_t)(bi * 128 + wave * 16       + srw) * DDIM + scl;
    const ushort* Ag1 = X + (size_t)(bi * 128 + (wave + 4) * 16 + srw) * DDIM + scl;
    const ushort* Bg0 = X + (size_t)(bj * 128 + wave * 16       + srw) * DDIM + scl;
    const ushort* Bg1 = X + (size_t)(bj * 128 + (wave + 4) * 16 + srw) * DDIM + scl;

    auto stage = [&](ushort* Al, ushort* Bl, int kk) {
        __builtin_amdgcn_global_load_lds(
            (const __attribute__((address_space(1))) unsigned int*)(Ag0 + kk),
            (__attribute__((address_space(3))) unsigned int*)(Al + wave * 512), 16, 0, 0);
        __builtin_amdgcn_global_load_lds(
            (const __attribute__((address_space(1))) unsigned int*)(Ag1 + kk),
            (__attribute__((address_space(3))) unsigned int*)(Al + (wave + 4) * 512), 16, 0, 0);
        __builtin_amdgcn_global_load_lds(
            (const __attribute__((address_space(1))) unsigned int*)(Bg0 + kk),
            (__attribute__((address_space(3))) unsigned int*)(Bl + wave * 512), 16, 0, 0);
        __builtin_amdgcn_global_load_lds(
            (const __attribute__((address_space(1))) unsigned int*)(Bg1 + kk),
            (__attribute__((address_space(3))) unsigned int*)(Bl + (wave + 4) * 512), 16, 0, 0);
    };
    auto compute = [&](const ushort* Al, const ushort* Bl) {
        bf16x8 a[4], b[4];
#pragma unroll
        for (int t = 0; t < 4; t++)
            a[t] = *(const bf16x8*)(Al + (wm * 64 + t * 16 + l16) * 32 + quad * 8);
#pragma unroll
        for (int t = 0; t < 4; t++)
            b[t] = *(const bf16x8*)(Bl + (wn * 64 + t * 16 + l16) * 32 + quad * 8);
#pragma unroll
        for (int mt = 0; mt < 4; mt++)
#pragma unroll
            for (int nt = 0; nt < 4; nt++)
                acc_r[mt][nt] = __builtin_amdgcn_mfma_f32_16x16x32_bf16(
                    a[mt], b[nt], acc_r[mt][nt], 0, 0, 0);
    };

    constexpr int KS = DDIM / NKZ;
    const int k0 = kz * KS, k1 = k0 + KS;

    // Prologue: fill buf0, drain, barrier.
    stage(As0, Bs0, k0);
    asm volatile("s_waitcnt vmcnt(0)" ::: "memory");
    __builtin_amdgcn_s_barrier();

    // Main loop: two K-steps (buf0, buf1) per iteration; static buffer names
    // (no runtime cur index -> no scratch). One drain+barrier per K-step,
    // placed AFTER the MFMAs so the prefetch overlaps compute.
    for (int kk = k0; kk < k1; kk += 64) {
        stage(As1, Bs1, kk + 32);            // prefetch next K-step
        compute(As0, Bs0);                   // compute current (prev staged)
        asm volatile("s_waitcnt vmcnt(0)" ::: "memory");
        __builtin_amdgcn_s_barrier();        // buf1 ready; buf0 reads done
        if (kk + 64 < k1) {
            stage(As0, Bs0, kk + 64);
            compute(As1, Bs1);
            asm volatile("s_waitcnt vmcnt(0)" ::: "memory");
            __builtin_amdgcn_s_barrier();
        } else {
            compute(As1, Bs1);               // tail: nothing left to prefetch
        }
    }

    // Epilogue: C/D layout col = lane&15, row = quad*4 + reg. Writes 2*acc
    // (the /TEMP) into this K-slice's partial buffer.
    float* Cp = Cpart + (size_t)kz * KROWS * KROWS;
#pragma unroll
    for (int mt = 0; mt < 4; mt++) {
#pragma unroll
        for (int r = 0; r < 4; r++) {
            const int row = bi * 128 + wm * 64 + mt * 16 + quad * 4 + r;
            float* o = Cp + (size_t)row * KROWS + bj * 128 + wn * 64 + l16;
#pragma unroll
            for (int nt = 0; nt < 4; nt++) o[nt * 16] = 2.0f * acc_r[mt][nt][r];
        }
    }
}

// ---------------- standalone MSE (fallback sequential path) ----------------
__global__ __launch_bounds__(256) void mse_kernel(const float* __restrict__ pic,
                                                  const float* __restrict__ dec,
                                                  float* __restrict__ acc) {
    mse_block(pic, dec, acc, blockIdx.y, blockIdx.x);
}

// ---------------- K4: per-row fixed-shift LSE + positives (+finalize) -------
// Entries are 2*cos_sim <= 2.0 -> fixed shift of 2.0 (no max pass). Last
// block to finish (device-scope counter) performs the finalize.
template<int NKZ>
__global__ void lse_kernel(const float* __restrict__ Cpart,
                           float* __restrict__ acc,
                           float* __restrict__ out) {
    const int i = blockIdx.x;
    __shared__ float srow[KROWS];      // 8 KB
    const float* r0 = Cpart + (size_t)i * KROWS;
    for (int j = threadIdx.x * 4; j < KROWS; j += blockDim.x * 4) {
        float4 s = *(const float4*)(r0 + j);
#pragma unroll
        for (int p = 1; p < NKZ; p++) {
            float4 b = *(const float4*)(r0 + (size_t)p * KROWS * KROWS + j);
            s.x += b.x; s.y += b.y; s.z += b.z; s.w += b.w;
        }
        *(float4*)(srow + j) = s;
    }
    __syncthreads();

    const int ires = i & (BSZ - 1);
    float se = 0.0f;
    for (int j = threadIdx.x; j < KROWS; j += blockDim.x)
        if ((j & (BSZ - 1)) != ires) se += __expf(srow[j] - 2.0f);
    se = blockReduceSum(se);

    if (threadIdx.x == 0) {
        const float neg_lse = 2.0f + __logf(se);
        float loss = 0.0f;
#pragma unroll
        for (int t = 0; t < N_T; t++) {
            const int j = ires + t * BSZ;
            if (j == i) continue;
            const float x = neg_lse - srow[j];   // logaddexp(L,p)-p = softplus(L-p)
            loss += (x > 0.0f) ? (x + log1pf(expf(-x))) : log1pf(expf(x));
        }
        atomicAdd(acc + 1, loss);
        __threadfence();
        const int old = atomicAdd((int*)acc + 8, 1);
        if (old == KROWS - 1) {
            // Atomic RMW read-back guarantees device-scope freshness.
            const float mse = atomicAdd(acc + 0, 0.0f);
            const float lh  = atomicAdd(acc + 1, 0.0f);
            out[0] = mse / (float)T_MSE + lh / (float)KPOS;
        }
    }
}

extern "C" void kernel_launch(void* const* d_in, const int* in_sizes, int n_in,
                              void* d_out, int out_size, void* d_ws, size_t ws_size,
                              hipStream_t stream) {
    const float* pic = (const float*)d_in[0];
    float* dec = (float*)d_in[1];
    const float* h = (const float*)d_in[2];
    float* out = (float*)d_out;

    float* acc = (float*)d_ws;  // acc[0]=mse, acc[1]=loss_h, int idx 8=done-counter
    const size_t hbuf_bytes = (size_t)KROWS * DDIM * sizeof(__hip_bfloat16);   // 16 MB
    const size_t part_bytes = (size_t)KROWS * KROWS * sizeof(float);           // 16.78 MB

    if (ws_size >= 256 + hbuf_bytes + 2 * part_bytes) {
        // Main path: 3 dispatches, MSE fused into the GEMM launch.
        __hip_bfloat16* hbuf = (__hip_bfloat16*)((char*)d_ws + 256);
        float* Cpart = (float*)((char*)d_ws + 256 + hbuf_bytes);
        norm_kernel<<<KROWS, 256, 0, stream>>>(h, hbuf, acc, 1);
        mega_kernel<2><<<2 * 256 + MSE_BLOCKS, 256, 0, stream>>>(
            (const ushort*)hbuf, Cpart, pic, dec, acc);
        lse_kernel<2><<<KROWS, 256, 0, stream>>>(Cpart, acc, out);
    } else {
        // Fallback: dec buffer as scratch. MSE must fully consume dec BEFORE
        // norm/gemm overwrite it -> strictly sequential kernels.
        hipMemsetAsync(d_ws, 0, 256, stream);
        __hip_bfloat16* hbuf = (__hip_bfloat16*)dec;
        float* Cpart = (float*)((char*)dec + hbuf_bytes);
        mse_kernel<<<dim3(MSE_BLOCKS / N_T, N_T), 256, 0, stream>>>(pic, dec, acc);
        norm_kernel<<<KROWS, 256, 0, stream>>>(h, hbuf, acc, 0);
        mega_kernel<2><<<2 * 256, 256, 0, stream>>>(
            (const ushort*)hbuf, Cpart, pic, dec, acc);
        lse_kernel<2><<<KROWS, 256, 0, stream>>>(Cpart, acc, out);
    }
}